// Round 1
// baseline (221.262 us; speedup 1.0000x reference)
//
#include <hip/hip_runtime.h>

// SymmetricChannel: out[b,l,:] = one_hot(shifted replacement) if
// (rand_u[b,l] < P && argmax(message[b,l,:]) != 0) else message[b,l,:].
// V=128 floats per row. 32 lanes per row, float4 per lane (16B), wave-local
// shfl_xor argmax reduction over the 32-lane half-wave.

constexpr int V = 128;
constexpr float P = 0.1f;

__global__ __launch_bounds__(256) void SymmetricChannel_kernel(
    const float* __restrict__ msg,
    const float* __restrict__ rand_u,
    const int*   __restrict__ rep_idx,
    float*       __restrict__ out,
    int n_rows)
{
    int tid    = blockIdx.x * blockDim.x + threadIdx.x;
    int row    = tid >> 5;      // 32 lanes per row
    int lane32 = tid & 31;
    if (row >= n_rows) return;

    const float4* mrow = (const float4*)(msg + (size_t)row * V);
    float4 v = mrow[lane32];

    // Local argmax over 4 elems, first-occurrence tie-break (strict >).
    float best = v.x; int bidx = 0;
    if (v.y > best) { best = v.y; bidx = 1; }
    if (v.z > best) { best = v.z; bidx = 2; }
    if (v.w > best) { best = v.w; bidx = 3; }
    int gidx = lane32 * 4 + bidx;

    // Butterfly reduce across the 32-lane half-wave.
    // Combine rule: larger value wins; on tie, smaller index (jnp.argmax = first occurrence).
    #pragma unroll
    for (int m = 16; m > 0; m >>= 1) {
        float ov = __shfl_xor(best, m, 32);
        int   oi = __shfl_xor(gidx, m, 32);
        if (ov > best || (ov == best && oi < gidx)) { best = ov; gidx = oi; }
    }

    int   am = gidx;                 // argmax(message[row])
    float ru = rand_u[row];
    bool combined = (ru < P) && (am != 0);

    float4 o;
    if (combined) {
        // msg_exp == am here (am != 0 guaranteed on this path).
        int r1  = rep_idx[row] + 1;
        int sym = r1 + (r1 >= am ? 1 : 0);
        int base = lane32 * 4;
        o.x = (base + 0 == sym) ? 1.0f : 0.0f;
        o.y = (base + 1 == sym) ? 1.0f : 0.0f;
        o.z = (base + 2 == sym) ? 1.0f : 0.0f;
        o.w = (base + 3 == sym) ? 1.0f : 0.0f;
    } else {
        o = v;
    }
    ((float4*)(out + (size_t)row * V))[lane32] = o;
}

extern "C" void kernel_launch(void* const* d_in, const int* in_sizes, int n_in,
                              void* d_out, int out_size, void* d_ws, size_t ws_size,
                              hipStream_t stream) {
    const float* msg = (const float*)d_in[0];   // [B, L, V] f32
    const float* ru  = (const float*)d_in[1];   // [B, L]    f32
    const int*   ri  = (const int*)d_in[2];     // [B, L]    i32
    float* out = (float*)d_out;                 // [B, L, V] f32

    int n_rows = in_sizes[1];                   // B*L
    int threads = 256;
    long long total = (long long)n_rows * 32;
    int blocks = (int)((total + threads - 1) / threads);
    SymmetricChannel_kernel<<<blocks, threads, 0, stream>>>(msg, ru, ri, out, n_rows);
}